// Round 1
// baseline (425.020 us; speedup 1.0000x reference)
//
#include <hip/hip_runtime.h>

// Problem constants (B=2, S=2048, HID=2048, H=16, D=128)
#define S_LEN 2048
#define HID_DIM 2048
#define NH 16
#define HD 128
#define N3 6144
#define M_ROWS 4096

typedef __bf16 bf16x8 __attribute__((ext_vector_type(8)));
typedef float f32x4 __attribute__((ext_vector_type(4)));

#define MFMA16(a, b, c) __builtin_amdgcn_mfma_f32_16x16x32_bf16(a, b, c, 0, 0, 0)

__device__ __forceinline__ unsigned short f2bf(float f) {
  union { float f; unsigned u; } v; v.f = f;
  return (unsigned short)((v.u + 0x7fffu + ((v.u >> 16) & 1u)) >> 16);
}
__device__ __forceinline__ float bf2f(unsigned short h) {
  union { unsigned u; float f; } v; v.u = ((unsigned)h) << 16; return v.f;
}
__device__ __forceinline__ void store_c(float* p, float v) { *p = v; }
__device__ __forceinline__ void store_c(unsigned short* p, float v) { *p = f2bf(v); }

// async global->LDS, 16B per lane; LDS dest = wave-uniform base + lane*16
__device__ __forceinline__ void async16(const void* g, void* l) {
  __builtin_amdgcn_global_load_lds((const __attribute__((address_space(1))) unsigned int*)g,
                                   (__attribute__((address_space(3))) unsigned int*)l,
                                   16, 0, 0);
}

// ---------------- elementwise cast f32 -> bf16 (vectorized) ----------------
__global__ __launch_bounds__(256) void cast_bf16(const float4* __restrict__ src,
                                                 ushort4* __restrict__ dst) {
  int i = blockIdx.x * 256 + threadIdx.x;
  float4 v = src[i];
  ushort4 o;
  o.x = f2bf(v.x); o.y = f2bf(v.y); o.z = f2bf(v.z); o.w = f2bf(v.w);
  dst[i] = o;
}

// ---------------- transpose + cast: src[R][C] f32 -> dst[C][R] bf16 ----------------
__global__ __launch_bounds__(256) void transpose_cast(const float* __restrict__ src,
                                                      unsigned short* __restrict__ dst,
                                                      int R, int Ccols) {
  __shared__ float t[32][33];
  int ct = Ccols >> 5;
  int bx = blockIdx.x % ct, by = blockIdx.x / ct;
  int c0 = bx << 5, r0 = by << 5;
  int lx = threadIdx.x & 31, ly = threadIdx.x >> 5;
#pragma unroll
  for (int i = 0; i < 32; i += 8)
    t[ly + i][lx] = src[(long long)(r0 + ly + i) * Ccols + c0 + lx];
  __syncthreads();
#pragma unroll
  for (int i = 0; i < 32; i += 8)
    dst[(long long)(c0 + ly + i) * R + r0 + lx] = f2bf(t[lx][ly + i]);
}

// ---------------- RoPE tables: cos/sin[s][i], i in [0,64) ----------------
__global__ __launch_bounds__(256) void rope_tables(float* __restrict__ cosT,
                                                   float* __restrict__ sinT) {
  int idx = blockIdx.x * 256 + threadIdx.x;  // S*64 entries
  int s = idx >> 6, i = idx & 63;
  float invf = powf(10000.0f, -(float)i * (1.0f / 64.0f));
  float a = (float)s * invf;
  cosT[idx] = cosf(a);
  sinT[idx] = sinf(a);
}

// ---------------- GEMM: C[M][N] = A[M][K] * Bt[N][K]^T, bf16 in, f32 acc ----------------
// m97 structure: 128x128 tile, BK=32, 4 waves (each 64x64 = 4x4 mfma_16x16x32), global_load_lds w16.
template <typename OutT>
__global__ __launch_bounds__(256) void gemm_bt(const unsigned short* __restrict__ A,
                                               const unsigned short* __restrict__ Bt,
                                               OutT* __restrict__ C,
                                               int Mdim, int Ndim, int Kdim) {
  __shared__ unsigned short As[128 * 32];
  __shared__ unsigned short Bs[128 * 32];
  const int ntn = Ndim >> 7;
  const int tm = (blockIdx.x / ntn) << 7;
  const int tn = (blockIdx.x % ntn) << 7;
  const int tid = threadIdx.x;
  const int w = tid >> 6, l = tid & 63;
  const int g = l >> 4, cc = l & 15;
  const int wm = (w >> 1) << 6;
  const int wn = (w & 1) << 6;
  f32x4 acc[4][4] = {};

  const int srow = (w << 5) + (l >> 2);      // staging row (call 0), +16 for call 1
  const int scol = (l & 3) << 3;             // element col within 32 (16B chunks)
  const unsigned short* ga = A + (long long)(tm + srow) * Kdim + scol;
  const unsigned short* gb = Bt + (long long)(tn + srow) * Kdim + scol;
  unsigned short* la0 = As + ((w << 5) << 5);
  unsigned short* la1 = As + (((w << 5) + 16) << 5);
  unsigned short* lb0 = Bs + ((w << 5) << 5);
  unsigned short* lb1 = Bs + (((w << 5) + 16) << 5);

  const int nk = Kdim >> 5;
  for (int kt = 0; kt < nk; ++kt) {
    __syncthreads();
    async16(ga, la0);
    async16(ga + 16 * Kdim, la1);
    async16(gb, lb0);
    async16(gb + 16 * Kdim, lb1);
    ga += 32; gb += 32;
    __syncthreads();  // drains vmcnt(0): LDS ready

    bf16x8 af[4], bfr[4];
#pragma unroll
    for (int i = 0; i < 4; ++i)
      af[i] = *(const bf16x8*)(As + ((wm + (i << 4) + cc) << 5) + (g << 3));
#pragma unroll
    for (int j = 0; j < 4; ++j)
      bfr[j] = *(const bf16x8*)(Bs + ((wn + (j << 4) + cc) << 5) + (g << 3));
#pragma unroll
    for (int i = 0; i < 4; ++i)
#pragma unroll
      for (int j = 0; j < 4; ++j)
        acc[i][j] = MFMA16(af[i], bfr[j], acc[i][j]);
  }

#pragma unroll
  for (int i = 0; i < 4; ++i)
#pragma unroll
    for (int j = 0; j < 4; ++j)
#pragma unroll
      for (int p = 0; p < 4; ++p) {
        int row = tm + wm + (i << 4) + (g << 2) + p;
        int col = tn + wn + (j << 4) + cc;
        store_c(&C[(long long)row * Ndim + col], acc[i][j][p]);
      }
}

// ---------------- split qkv -> Q,K (RoPE, [B,H,S,D]) and Vt ([B,H,D,S]) ----------------
__global__ __launch_bounds__(256) void split_rope(const unsigned short* __restrict__ qkv,
                                                  const float* __restrict__ cosT,
                                                  const float* __restrict__ sinT,
                                                  unsigned short* __restrict__ Qb,
                                                  unsigned short* __restrict__ Kb,
                                                  unsigned short* __restrict__ Vt) {
  __shared__ unsigned short vtile[32][128];
  const int bid = blockIdx.x;
  const int st = bid & 63;           // S/32 tiles
  const int h = (bid >> 6) & 15;
  const int b = bid >> 10;
  const int s0 = st << 5;
  const int t = threadIdx.x;
  const int d = t & 127;
  const int sl0 = t >> 7;
  const int dh = d & 63;
  const float sgn = (d < 64) ? -1.0f : 1.0f;
#pragma unroll
  for (int it = 0; it < 16; ++it) {
    const int sl = sl0 + (it << 1);
    const int s = s0 + sl;
    const long long rb = ((long long)(b * S_LEN + s)) * N3 + h * HD;
    const float cv = cosT[(s << 6) + dh];
    const float sv = sinT[(s << 6) + dh];
    float qv = bf2f(qkv[rb + d]);
    float qo = bf2f(qkv[rb + (d ^ 64)]);
    float kv = bf2f(qkv[rb + HID_DIM + d]);
    float ko = bf2f(qkv[rb + HID_DIM + (d ^ 64)]);
    const long long ob = ((long long)((b * NH + h) * S_LEN + s)) * HD + d;
    Qb[ob] = f2bf(qv * cv + sgn * qo * sv);
    Kb[ob] = f2bf(kv * cv + sgn * ko * sv);
    vtile[sl][d] = qkv[rb + 2 * HID_DIM + d];
  }
  __syncthreads();
  const int dr = t >> 1;
  const int sh = (t & 1) << 4;
  unsigned short tv[16];
#pragma unroll
  for (int j = 0; j < 16; ++j) tv[j] = vtile[sh + j][dr];
  uint4 u0, u1;
  u0.x = (unsigned)tv[0] | ((unsigned)tv[1] << 16);
  u0.y = (unsigned)tv[2] | ((unsigned)tv[3] << 16);
  u0.z = (unsigned)tv[4] | ((unsigned)tv[5] << 16);
  u0.w = (unsigned)tv[6] | ((unsigned)tv[7] << 16);
  u1.x = (unsigned)tv[8] | ((unsigned)tv[9] << 16);
  u1.y = (unsigned)tv[10] | ((unsigned)tv[11] << 16);
  u1.z = (unsigned)tv[12] | ((unsigned)tv[13] << 16);
  u1.w = (unsigned)tv[14] | ((unsigned)tv[15] << 16);
  const long long vb = ((long long)((b * NH + h) * HD + dr)) * S_LEN + s0 + sh;
  *(uint4*)(Vt + vb) = u0;
  *(uint4*)(Vt + vb + 8) = u1;
}

// ---------------- flash attention: causal, online softmax ----------------
// grid: 32 q-tiles (64 rows) x 32 (b,h); 4 waves, each owns 16 q-rows.
__global__ __launch_bounds__(256) void flash_attn(const unsigned short* __restrict__ Qg,
                                                  const unsigned short* __restrict__ Kg,
                                                  const unsigned short* __restrict__ Vt,
                                                  unsigned short* __restrict__ Og) {
  __shared__ unsigned short Ks[64 * 128];   // [kv][d], chunk-swizzled
  __shared__ unsigned short Vs[128 * 64];   // [d][kv], chunk-swizzled
  __shared__ unsigned short Ps[4][16 * 64]; // per-wave P, chunk-swizzled
  const int qt = blockIdx.x & 31;
  const int bh = blockIdx.x >> 5;
  const int q0 = qt << 6;
  const long long base = (long long)bh * (S_LEN * HD);
  const int tid = threadIdx.x, w = tid >> 6, l = tid & 63;
  const int g = l >> 4, c = l & 15;

  // Q fragments (A operand), rows q0 + w*16 + c, k-slices over D
  bf16x8 aq[4];
  {
    const long long qr = base + (long long)(q0 + (w << 4) + c) * HD;
#pragma unroll
    for (int kk = 0; kk < 4; ++kk)
      aq[kk] = *(const bf16x8*)(Qg + qr + (kk << 5) + (g << 3));
  }
  f32x4 oacc[8] = {};
  float mrow[4], lrow[4];
#pragma unroll
  for (int p = 0; p < 4; ++p) { mrow[p] = -1e30f; lrow[p] = 0.f; }

  const int ntile = qt + 1;
  for (int t = 0; t < ntile; ++t) {
    const int kv0 = t << 6;
    __syncthreads();
    // stage K tile [64][128]: source chunk pre-swizzled so reads can XOR-deswizzle
#pragma unroll
    for (int j = 0; j < 4; ++j) {
      int row = (w << 4) + (j << 2) + g;
      int chunk = c ^ (row & 7);
      async16(Kg + base + (long long)(kv0 + row) * HD + (chunk << 3),
              Ks + (((w << 4) + (j << 2)) << 7));
    }
    // stage Vt tile [128][64]
#pragma unroll
    for (int j = 0; j < 4; ++j) {
      int dr = (w << 5) + (j << 3) + (l >> 3);
      int chunk = (l & 7) ^ (dr & 7);
      async16(Vt + base + (long long)dr * S_LEN + kv0 + (chunk << 3),
              Vs + (((w << 5) + (j << 3)) << 6));
    }
    __syncthreads();

    // S = Q K^T (per wave: 16 q x 64 kv)
    f32x4 sc[4] = {};
#pragma unroll
    for (int cb = 0; cb < 4; ++cb) {
      int krow = (cb << 4) + c;
      const char* kbase = (const char*)Ks + krow * 256;
#pragma unroll
      for (int kk = 0; kk < 4; ++kk) {
        bf16x8 bk = *(const bf16x8*)(kbase + (((kk << 6) + (g << 4)) ^ ((krow & 7) << 4)));
        sc[cb] = MFMA16(aq[kk], bk, sc[cb]);
      }
    }
    const float scale = 0.08838834764831845f;  // 1/sqrt(128)
#pragma unroll
    for (int cb = 0; cb < 4; ++cb)
#pragma unroll
      for (int p = 0; p < 4; ++p) sc[cb][p] *= scale;

    if (t == ntile - 1) {  // diagonal tile: mask col > row
#pragma unroll
      for (int cb = 0; cb < 4; ++cb) {
        int col = kv0 + (cb << 4) + c;
#pragma unroll
        for (int p = 0; p < 4; ++p) {
          int row = q0 + (w << 4) + (g << 2) + p;
          if (col > row) sc[cb][p] = -1e30f;
        }
      }
    }

    // online softmax (wave-parallel; rows live in 16-lane groups)
    float fsc[4];
#pragma unroll
    for (int p = 0; p < 4; ++p) {
      float m0 = fmaxf(fmaxf(sc[0][p], sc[1][p]), fmaxf(sc[2][p], sc[3][p]));
      m0 = fmaxf(m0, __shfl_xor(m0, 1));
      m0 = fmaxf(m0, __shfl_xor(m0, 2));
      m0 = fmaxf(m0, __shfl_xor(m0, 4));
      m0 = fmaxf(m0, __shfl_xor(m0, 8));
      float mn = fmaxf(mrow[p], m0);
      fsc[p] = __expf(mrow[p] - mn);
      mrow[p] = mn;
      float s = 0.f;
#pragma unroll
      for (int cb = 0; cb < 4; ++cb) {
        float pv = __expf(sc[cb][p] - mn);
        sc[cb][p] = pv;
        s += pv;
      }
      s += __shfl_xor(s, 1); s += __shfl_xor(s, 2);
      s += __shfl_xor(s, 4); s += __shfl_xor(s, 8);
      lrow[p] = lrow[p] * fsc[p] + s;
    }
#pragma unroll
    for (int db = 0; db < 8; ++db)
#pragma unroll
      for (int p = 0; p < 4; ++p) oacc[db][p] *= fsc[p];

    // P -> LDS (per-wave region, swizzled), then PV
    char* pb = (char*)&Ps[w][0];
#pragma unroll
    for (int cb = 0; cb < 4; ++cb)
#pragma unroll
      for (int p = 0; p < 4; ++p) {
        int row = (g << 2) + p;
        int colb = ((cb << 4) + c) << 1;
        *(unsigned short*)(pb + (row << 7) + (colb ^ ((row & 7) << 4))) = f2bf(sc[cb][p]);
      }
    asm volatile("s_waitcnt lgkmcnt(0)" ::: "memory");
    __builtin_amdgcn_sched_barrier(0);
#pragma unroll
    for (int hf = 0; hf < 2; ++hf) {
      bf16x8 ap = *(const bf16x8*)(pb + (c << 7) + (((hf << 6) + (g << 4)) ^ ((c & 7) << 4)));
#pragma unroll
      for (int db = 0; db < 8; ++db) {
        int vrow = (db << 4) + c;
        bf16x8 bv = *(const bf16x8*)((const char*)Vs + (vrow << 7) +
                                     (((hf << 6) + (g << 4)) ^ ((vrow & 7) << 4)));
        oacc[db] = MFMA16(ap, bv, oacc[db]);
      }
    }
  }

  // epilogue: O[b*S + q][h*128 + d] bf16
  const int b = bh >> 4, h = bh & 15;
#pragma unroll
  for (int db = 0; db < 8; ++db)
#pragma unroll
    for (int p = 0; p < 4; ++p) {
      int row = (b << 11) + q0 + (w << 4) + (g << 2) + p;
      int col = (h << 7) + (db << 4) + c;
      Og[(long long)row * HID_DIM + col] = f2bf(oacc[db][p] / lrow[p]);
    }
}

// ---------------- launch ----------------
extern "C" void kernel_launch(void* const* d_in, const int* in_sizes, int n_in,
                              void* d_out, int out_size, void* d_ws, size_t ws_size,
                              hipStream_t stream) {
  (void)in_sizes; (void)n_in; (void)out_size; (void)ws_size;
  const float* x = (const float*)d_in[0];
  const float* w_qkv = (const float*)d_in[1];
  const float* w_out = (const float*)d_in[2];
  float* out = (float*)d_out;
  char* ws = (char*)d_ws;

  // workspace layout (total 152,043,520 bytes)
  unsigned short* xb    = (unsigned short*)(ws);              // 16 MB  [4096][2048]
  unsigned short* wqkvT = (unsigned short*)(ws + 16777216);   // 24 MB  [6144][2048]
  unsigned short* woutT = (unsigned short*)(ws + 41943040);   //  8 MB  [2048][2048]
  unsigned short* qkv   = (unsigned short*)(ws + 50331648);   // 48 MB  [4096][6144] (reused as O)
  unsigned short* Qb    = (unsigned short*)(ws + 100663296);  // 16 MB  [B,H,S,D]
  unsigned short* Kb    = (unsigned short*)(ws + 117440512);  // 16 MB  [B,H,S,D]
  unsigned short* Vt    = (unsigned short*)(ws + 134217728);  // 16 MB  [B,H,D,S]
  float* cosT = (float*)(ws + 150994944);                     // 0.5 MB [S][64]
  float* sinT = (float*)(ws + 151519232);                     // 0.5 MB
  unsigned short* Ob = qkv;

  cast_bf16<<<8192, 256, 0, stream>>>((const float4*)x, (ushort4*)xb);
  transpose_cast<<<12288, 256, 0, stream>>>(w_qkv, wqkvT, 2048, 6144);
  transpose_cast<<<4096, 256, 0, stream>>>(w_out, woutT, 2048, 2048);
  rope_tables<<<512, 256, 0, stream>>>(cosT, sinT);
  gemm_bt<unsigned short><<<1536, 256, 0, stream>>>(xb, wqkvT, qkv, 4096, 6144, 2048);
  split_rope<<<2048, 256, 0, stream>>>(qkv, cosT, sinT, Qb, Kb, Vt);
  flash_attn<<<1024, 256, 0, stream>>>(Qb, Kb, Vt, Ob);
  gemm_bt<float><<<512, 256, 0, stream>>>(Ob, woutT, out, 4096, 2048, 2048);
}

// Round 2
// 420.519 us; speedup vs baseline: 1.0107x; 1.0107x over previous
//
#include <hip/hip_runtime.h>

// Problem constants (B=2, S=2048, HID=2048, H=16, D=128)
#define S_LEN 2048
#define HID_DIM 2048
#define NH 16
#define HD 128
#define N3 6144
#define M_ROWS 4096

typedef __bf16 bf16x8 __attribute__((ext_vector_type(8)));
typedef float f32x4 __attribute__((ext_vector_type(4)));

#define MFMA16(a, b, c) __builtin_amdgcn_mfma_f32_16x16x32_bf16(a, b, c, 0, 0, 0)

__device__ __forceinline__ unsigned short f2bf(float f) {
  union { float f; unsigned u; } v; v.f = f;
  return (unsigned short)((v.u + 0x7fffu + ((v.u >> 16) & 1u)) >> 16);
}
__device__ __forceinline__ float bf2f(unsigned short h) {
  union { unsigned u; float f; } v; v.u = ((unsigned)h) << 16; return v.f;
}
__device__ __forceinline__ void store_c(float* p, float v) { *p = v; }
__device__ __forceinline__ void store_c(unsigned short* p, float v) { *p = f2bf(v); }

// async global->LDS, 16B per lane; LDS dest = wave-uniform base + lane*16
__device__ __forceinline__ void async16(const void* g, void* l) {
  __builtin_amdgcn_global_load_lds((const __attribute__((address_space(1))) unsigned int*)g,
                                   (__attribute__((address_space(3))) unsigned int*)l,
                                   16, 0, 0);
}

// ---------------- elementwise cast f32 -> bf16 (vectorized) ----------------
__global__ __launch_bounds__(256) void cast_bf16(const float4* __restrict__ src,
                                                 ushort4* __restrict__ dst) {
  int i = blockIdx.x * 256 + threadIdx.x;
  float4 v = src[i];
  ushort4 o;
  o.x = f2bf(v.x); o.y = f2bf(v.y); o.z = f2bf(v.z); o.w = f2bf(v.w);
  dst[i] = o;
}

// ---------------- transpose + cast: src[R][C] f32 -> dst[C][R] bf16 ----------------
__global__ __launch_bounds__(256) void transpose_cast(const float* __restrict__ src,
                                                      unsigned short* __restrict__ dst,
                                                      int R, int Ccols) {
  __shared__ float t[32][33];
  int ct = Ccols >> 5;
  int bx = blockIdx.x % ct, by = blockIdx.x / ct;
  int c0 = bx << 5, r0 = by << 5;
  int lx = threadIdx.x & 31, ly = threadIdx.x >> 5;
#pragma unroll
  for (int i = 0; i < 32; i += 8)
    t[ly + i][lx] = src[(long long)(r0 + ly + i) * Ccols + c0 + lx];
  __syncthreads();
#pragma unroll
  for (int i = 0; i < 32; i += 8)
    dst[(long long)(c0 + ly + i) * R + r0 + lx] = f2bf(t[lx][ly + i]);
}

// ---------------- RoPE tables: cos/sin[s][i], i in [0,64) ----------------
__global__ __launch_bounds__(256) void rope_tables(float* __restrict__ cosT,
                                                   float* __restrict__ sinT) {
  int idx = blockIdx.x * 256 + threadIdx.x;  // S*64 entries
  int s = idx >> 6, i = idx & 63;
  float invf = powf(10000.0f, -(float)i * (1.0f / 64.0f));
  float a = (float)s * invf;
  cosT[idx] = cosf(a);
  sinT[idx] = sinf(a);
}

// ---------------- GEMM: C[M][N] = A[M][K] * Bt[N][K]^T, bf16 in, f32 acc ----------------
template <typename OutT>
__global__ __launch_bounds__(256) void gemm_bt(const unsigned short* __restrict__ A,
                                               const unsigned short* __restrict__ Bt,
                                               OutT* __restrict__ C,
                                               int Mdim, int Ndim, int Kdim) {
  __shared__ unsigned short As[128 * 32];
  __shared__ unsigned short Bs[128 * 32];
  const int ntn = Ndim >> 7;
  const int tm = (blockIdx.x / ntn) << 7;
  const int tn = (blockIdx.x % ntn) << 7;
  const int tid = threadIdx.x;
  const int w = tid >> 6, l = tid & 63;
  const int g = l >> 4, cc = l & 15;
  const int wm = (w >> 1) << 6;
  const int wn = (w & 1) << 6;
  f32x4 acc[4][4] = {};

  const int srow = (w << 5) + (l >> 2);
  const int scol = (l & 3) << 3;
  const unsigned short* ga = A + (long long)(tm + srow) * Kdim + scol;
  const unsigned short* gb = Bt + (long long)(tn + srow) * Kdim + scol;
  unsigned short* la0 = As + ((w << 5) << 5);
  unsigned short* la1 = As + (((w << 5) + 16) << 5);
  unsigned short* lb0 = Bs + ((w << 5) << 5);
  unsigned short* lb1 = Bs + (((w << 5) + 16) << 5);

  const int nk = Kdim >> 5;
  for (int kt = 0; kt < nk; ++kt) {
    __syncthreads();
    async16(ga, la0);
    async16(ga + 16 * Kdim, la1);
    async16(gb, lb0);
    async16(gb + 16 * Kdim, lb1);
    ga += 32; gb += 32;
    __syncthreads();

    bf16x8 af[4], bfr[4];
#pragma unroll
    for (int i = 0; i < 4; ++i)
      af[i] = *(const bf16x8*)(As + ((wm + (i << 4) + cc) << 5) + (g << 3));
#pragma unroll
    for (int j = 0; j < 4; ++j)
      bfr[j] = *(const bf16x8*)(Bs + ((wn + (j << 4) + cc) << 5) + (g << 3));
#pragma unroll
    for (int i = 0; i < 4; ++i)
#pragma unroll
      for (int j = 0; j < 4; ++j)
        acc[i][j] = MFMA16(af[i], bfr[j], acc[i][j]);
  }

#pragma unroll
  for (int i = 0; i < 4; ++i)
#pragma unroll
    for (int j = 0; j < 4; ++j)
#pragma unroll
      for (int p = 0; p < 4; ++p) {
        int row = tm + wm + (i << 4) + (g << 2) + p;
        int col = tn + wn + (j << 4) + cc;
        store_c(&C[(long long)row * Ndim + col], acc[i][j][p]);
      }
}

// ---------------- split qkv -> Q (pre-scaled),K (RoPE, [B,H,S,D]) and Vt ([B,H,D,S]) ----------------
__global__ __launch_bounds__(256) void split_rope(const unsigned short* __restrict__ qkv,
                                                  const float* __restrict__ cosT,
                                                  const float* __restrict__ sinT,
                                                  unsigned short* __restrict__ Qb,
                                                  unsigned short* __restrict__ Kb,
                                                  unsigned short* __restrict__ Vt) {
  __shared__ unsigned short vtile[32][128];
  const int bid = blockIdx.x;
  const int st = bid & 63;
  const int h = (bid >> 6) & 15;
  const int b = bid >> 10;
  const int s0 = st << 5;
  const int t = threadIdx.x;
  const int d = t & 127;
  const int sl0 = t >> 7;
  const int dh = d & 63;
  const float sgn = (d < 64) ? -1.0f : 1.0f;
  const float qscale = 0.08838834764831845f;  // 1/sqrt(128), baked into Q
#pragma unroll
  for (int it = 0; it < 16; ++it) {
    const int sl = sl0 + (it << 1);
    const int s = s0 + sl;
    const long long rb = ((long long)(b * S_LEN + s)) * N3 + h * HD;
    const float cv = cosT[(s << 6) + dh];
    const float sv = sinT[(s << 6) + dh];
    float qv = bf2f(qkv[rb + d]);
    float qo = bf2f(qkv[rb + (d ^ 64)]);
    float kv = bf2f(qkv[rb + HID_DIM + d]);
    float ko = bf2f(qkv[rb + HID_DIM + (d ^ 64)]);
    const long long ob = ((long long)((b * NH + h) * S_LEN + s)) * HD + d;
    Qb[ob] = f2bf((qv * cv + sgn * qo * sv) * qscale);
    Kb[ob] = f2bf(kv * cv + sgn * ko * sv);
    vtile[sl][d] = qkv[rb + 2 * HID_DIM + d];
  }
  __syncthreads();
  const int dr = t >> 1;
  const int sh = (t & 1) << 4;
  unsigned short tv[16];
#pragma unroll
  for (int j = 0; j < 16; ++j) tv[j] = vtile[sh + j][dr];
  uint4 u0, u1;
  u0.x = (unsigned)tv[0] | ((unsigned)tv[1] << 16);
  u0.y = (unsigned)tv[2] | ((unsigned)tv[3] << 16);
  u0.z = (unsigned)tv[4] | ((unsigned)tv[5] << 16);
  u0.w = (unsigned)tv[6] | ((unsigned)tv[7] << 16);
  u1.x = (unsigned)tv[8] | ((unsigned)tv[9] << 16);
  u1.y = (unsigned)tv[10] | ((unsigned)tv[11] << 16);
  u1.z = (unsigned)tv[12] | ((unsigned)tv[13] << 16);
  u1.w = (unsigned)tv[14] | ((unsigned)tv[15] << 16);
  const long long vb = ((long long)((b * NH + h) * HD + dr)) * S_LEN + s0 + sh;
  *(uint4*)(Vt + vb) = u0;
  *(uint4*)(Vt + vb + 8) = u1;
}

// ---------------- flash attention: causal, online softmax, double-buffered K/V ----------------
// grid: 32 q-tiles (64 rows, reversed for tail balance) x 32 (b,h); 4 waves x 16 q-rows.
__global__ __launch_bounds__(256) void flash_attn(const unsigned short* __restrict__ Qg,
                                                  const unsigned short* __restrict__ Kg,
                                                  const unsigned short* __restrict__ Vt,
                                                  unsigned short* __restrict__ Og) {
  __shared__ unsigned short Ks[2][64 * 128];   // [kv][d], chunk-swizzled
  __shared__ unsigned short Vs[2][128 * 64];   // [d][kv], chunk-swizzled
  __shared__ unsigned short Ps[4][16 * 64];    // per-wave P, chunk-swizzled
  const int id = blockIdx.x;
  const int qt = 31 - (id & 31);               // heavy blocks dispatch first
  const int bh = id >> 5;
  const int q0 = qt << 6;
  const long long base = (long long)bh * (S_LEN * HD);
  const int tid = threadIdx.x, w = tid >> 6, l = tid & 63;
  const int g = l >> 4, c = l & 15;

  // Q fragments (A operand), rows q0 + w*16 + c (Q is pre-scaled by 1/sqrt(D))
  bf16x8 aq[4];
  {
    const long long qr = base + (long long)(q0 + (w << 4) + c) * HD;
#pragma unroll
    for (int kk = 0; kk < 4; ++kk)
      aq[kk] = *(const bf16x8*)(Qg + qr + (kk << 5) + (g << 3));
  }
  f32x4 oacc[8] = {};
  float mrow[4], lrow[4];
#pragma unroll
  for (int p = 0; p < 4; ++p) { mrow[p] = -1e30f; lrow[p] = 0.f; }

  const int nt = qt + 1;

  // prologue: stage tile 0 into buffer 0
#pragma unroll
  for (int j = 0; j < 4; ++j) {
    int row = (w << 4) + (j << 2) + g;
    int chunk = c ^ (row & 7);
    async16(Kg + base + (long long)row * HD + (chunk << 3),
            &Ks[0][((w << 4) + (j << 2)) << 7]);
  }
#pragma unroll
  for (int j = 0; j < 4; ++j) {
    int dr = (w << 5) + (j << 3) + (l >> 3);
    int chunk = (l & 7) ^ (dr & 7);
    async16(Vt + base + (long long)dr * S_LEN + (chunk << 3),
            &Vs[0][((w << 5) + (j << 3)) << 6]);
  }
  __syncthreads();  // implicit vmcnt(0) drain: tile 0 ready

  int cur = 0;
  for (int t = 0; t < nt; ++t) {
    // issue next-tile prefetch FIRST; it drains at this iteration's closing barrier
    if (t + 1 < nt) {
      const int kn = (t + 1) << 6;
#pragma unroll
      for (int j = 0; j < 4; ++j) {
        int row = (w << 4) + (j << 2) + g;
        int chunk = c ^ (row & 7);
        async16(Kg + base + (long long)(kn + row) * HD + (chunk << 3),
                &Ks[cur ^ 1][((w << 4) + (j << 2)) << 7]);
      }
#pragma unroll
      for (int j = 0; j < 4; ++j) {
        int dr = (w << 5) + (j << 3) + (l >> 3);
        int chunk = (l & 7) ^ (dr & 7);
        async16(Vt + base + (long long)dr * S_LEN + kn + (chunk << 3),
                &Vs[cur ^ 1][((w << 5) + (j << 3)) << 6]);
      }
    }

    const unsigned short* ksb = &Ks[cur][0];
    const unsigned short* vsb = &Vs[cur][0];
    const int kv0 = t << 6;

    // S = Q K^T (per wave: 16 q x 64 kv); scale pre-baked into Q
    f32x4 sc[4] = {};
#pragma unroll
    for (int cb = 0; cb < 4; ++cb) {
      int krow = (cb << 4) + c;
      const char* kbase = (const char*)ksb + krow * 256;
#pragma unroll
      for (int kk = 0; kk < 4; ++kk) {
        bf16x8 bk = *(const bf16x8*)(kbase + (((kk << 6) + (g << 4)) ^ ((krow & 7) << 4)));
        sc[cb] = MFMA16(aq[kk], bk, sc[cb]);
      }
    }

    if (t == nt - 1) {  // diagonal tile: mask col > row
#pragma unroll
      for (int cb = 0; cb < 4; ++cb) {
        int col = kv0 + (cb << 4) + c;
#pragma unroll
        for (int p = 0; p < 4; ++p) {
          int row = q0 + (w << 4) + (g << 2) + p;
          if (col > row) sc[cb][p] = -1e30f;
        }
      }
    }

    // online softmax (wave-parallel; rows live in 16-lane groups)
    float fsc[4];
#pragma unroll
    for (int p = 0; p < 4; ++p) {
      float m0 = fmaxf(fmaxf(sc[0][p], sc[1][p]), fmaxf(sc[2][p], sc[3][p]));
      m0 = fmaxf(m0, __shfl_xor(m0, 1));
      m0 = fmaxf(m0, __shfl_xor(m0, 2));
      m0 = fmaxf(m0, __shfl_xor(m0, 4));
      m0 = fmaxf(m0, __shfl_xor(m0, 8));
      float mn = fmaxf(mrow[p], m0);
      fsc[p] = __expf(mrow[p] - mn);
      mrow[p] = mn;
      float s = 0.f;
#pragma unroll
      for (int cb = 0; cb < 4; ++cb) {
        float pv = __expf(sc[cb][p] - mn);
        sc[cb][p] = pv;
        s += pv;
      }
      s += __shfl_xor(s, 1); s += __shfl_xor(s, 2);
      s += __shfl_xor(s, 4); s += __shfl_xor(s, 8);
      lrow[p] = lrow[p] * fsc[p] + s;
    }
#pragma unroll
    for (int db = 0; db < 8; ++db)
#pragma unroll
      for (int p = 0; p < 4; ++p) oacc[db][p] *= fsc[p];

    // P -> LDS (per-wave region, swizzled), then PV
    char* pb = (char*)&Ps[w][0];
#pragma unroll
    for (int cb = 0; cb < 4; ++cb)
#pragma unroll
      for (int p = 0; p < 4; ++p) {
        int row = (g << 2) + p;
        int colb = ((cb << 4) + c) << 1;
        *(unsigned short*)(pb + (row << 7) + (colb ^ ((row & 7) << 4))) = f2bf(sc[cb][p]);
      }
    asm volatile("s_waitcnt lgkmcnt(0)" ::: "memory");
    __builtin_amdgcn_sched_barrier(0);
#pragma unroll
    for (int hf = 0; hf < 2; ++hf) {
      bf16x8 ap = *(const bf16x8*)(pb + (c << 7) + (((hf << 6) + (g << 4)) ^ ((c & 7) << 4)));
#pragma unroll
      for (int db = 0; db < 8; ++db) {
        int vrow = (db << 4) + c;
        bf16x8 bv = *(const bf16x8*)((const char*)vsb + (vrow << 7) +
                                     (((hf << 6) + (g << 4)) ^ ((vrow & 7) << 4)));
        oacc[db] = MFMA16(ap, bv, oacc[db]);
      }
    }

    __syncthreads();  // drains prefetch (vmcnt) + guards buffer reuse
    cur ^= 1;
  }

  // epilogue: O[b*S + q][h*128 + d] bf16
  const int b = bh >> 4, h = bh & 15;
#pragma unroll
  for (int db = 0; db < 8; ++db)
#pragma unroll
    for (int p = 0; p < 4; ++p) {
      int row = (b << 11) + q0 + (w << 4) + (g << 2) + p;
      int col = (h << 7) + (db << 4) + c;
      Og[(long long)row * HID_DIM + col] = f2bf(oacc[db][p] / lrow[p]);
    }
}

// ---------------- launch ----------------
extern "C" void kernel_launch(void* const* d_in, const int* in_sizes, int n_in,
                              void* d_out, int out_size, void* d_ws, size_t ws_size,
                              hipStream_t stream) {
  (void)in_sizes; (void)n_in; (void)out_size; (void)ws_size;
  const float* x = (const float*)d_in[0];
  const float* w_qkv = (const float*)d_in[1];
  const float* w_out = (const float*)d_in[2];
  float* out = (float*)d_out;
  char* ws = (char*)d_ws;

  unsigned short* xb    = (unsigned short*)(ws);              // 16 MB  [4096][2048]
  unsigned short* wqkvT = (unsigned short*)(ws + 16777216);   // 24 MB  [6144][2048]
  unsigned short* woutT = (unsigned short*)(ws + 41943040);   //  8 MB  [2048][2048]
  unsigned short* qkv   = (unsigned short*)(ws + 50331648);   // 48 MB  [4096][6144] (reused as O)
  unsigned short* Qb    = (unsigned short*)(ws + 100663296);  // 16 MB  [B,H,S,D]
  unsigned short* Kb    = (unsigned short*)(ws + 117440512);  // 16 MB  [B,H,S,D]
  unsigned short* Vt    = (unsigned short*)(ws + 134217728);  // 16 MB  [B,H,D,S]
  float* cosT = (float*)(ws + 150994944);                     // 0.5 MB [S][64]
  float* sinT = (float*)(ws + 151519232);                     // 0.5 MB
  unsigned short* Ob = qkv;

  cast_bf16<<<8192, 256, 0, stream>>>((const float4*)x, (ushort4*)xb);
  transpose_cast<<<12288, 256, 0, stream>>>(w_qkv, wqkvT, 2048, 6144);
  transpose_cast<<<4096, 256, 0, stream>>>(w_out, woutT, 2048, 2048);
  rope_tables<<<512, 256, 0, stream>>>(cosT, sinT);
  gemm_bt<unsigned short><<<1536, 256, 0, stream>>>(xb, wqkvT, qkv, 4096, 6144, 2048);
  split_rope<<<2048, 256, 0, stream>>>(qkv, cosT, sinT, Qb, Kb, Vt);
  flash_attn<<<1024, 256, 0, stream>>>(Qb, Kb, Vt, Ob);
  gemm_bt<float><<<512, 256, 0, stream>>>(Ob, woutT, out, 4096, 2048, 2048);
}

// Round 3
// 332.287 us; speedup vs baseline: 1.2791x; 1.2655x over previous
//
#include <hip/hip_runtime.h>
#include <hip/hip_bf16.h>

// Problem constants (B=2, S=2048, HID=2048, H=16, D=128)
#define S_LEN 2048
#define HID_DIM 2048
#define NH 16
#define HD 128
#define N3 6144

typedef __bf16 bf16x8 __attribute__((ext_vector_type(8)));
typedef float f32x4 __attribute__((ext_vector_type(4)));
typedef float f32x16 __attribute__((ext_vector_type(16)));

#define MFMA16(a, b, c) __builtin_amdgcn_mfma_f32_16x16x32_bf16(a, b, c, 0, 0, 0)
#define MFMA32(a, b, c) __builtin_amdgcn_mfma_f32_32x32x16_bf16(a, b, c, 0, 0, 0)

__device__ __forceinline__ unsigned short f2bf(float f) {
  union { float f; unsigned u; } v; v.f = f;
  return (unsigned short)((v.u + 0x7fffu + ((v.u >> 16) & 1u)) >> 16);
}
__device__ __forceinline__ float bf2f(unsigned short h) {
  union { unsigned u; float f; } v; v.u = ((unsigned)h) << 16; return v.f;
}
__device__ __forceinline__ unsigned packbf2(float lo, float hi) {
  union { __hip_bfloat162 h2; unsigned u; } cv;
  cv.h2 = __float22bfloat162_rn(make_float2(lo, hi));
  return cv.u;
}
__device__ __forceinline__ void store_c(float* p, float v) { *p = v; }
__device__ __forceinline__ void store_c(unsigned short* p, float v) { *p = f2bf(v); }

// async global->LDS, 16B per lane; LDS dest = wave-uniform base + lane*16
__device__ __forceinline__ void async16(const void* g, void* l) {
  __builtin_amdgcn_global_load_lds((const __attribute__((address_space(1))) unsigned int*)g,
                                   (__attribute__((address_space(3))) unsigned int*)l,
                                   16, 0, 0);
}

// ---------------- elementwise cast f32 -> bf16 (vectorized) ----------------
__global__ __launch_bounds__(256) void cast_bf16(const float4* __restrict__ src,
                                                 ushort4* __restrict__ dst) {
  int i = blockIdx.x * 256 + threadIdx.x;
  float4 v = src[i];
  ushort4 o;
  o.x = f2bf(v.x); o.y = f2bf(v.y); o.z = f2bf(v.z); o.w = f2bf(v.w);
  dst[i] = o;
}

// ---------------- transpose + cast: src[R][C] f32 -> dst[C][R] bf16 ----------------
__global__ __launch_bounds__(256) void transpose_cast(const float* __restrict__ src,
                                                      unsigned short* __restrict__ dst,
                                                      int R, int Ccols) {
  __shared__ float t[32][33];
  int ct = Ccols >> 5;
  int bx = blockIdx.x % ct, by = blockIdx.x / ct;
  int c0 = bx << 5, r0 = by << 5;
  int lx = threadIdx.x & 31, ly = threadIdx.x >> 5;
#pragma unroll
  for (int i = 0; i < 32; i += 8)
    t[ly + i][lx] = src[(long long)(r0 + ly + i) * Ccols + c0 + lx];
  __syncthreads();
#pragma unroll
  for (int i = 0; i < 32; i += 8)
    dst[(long long)(c0 + ly + i) * R + r0 + lx] = f2bf(t[lx][ly + i]);
}

// ---------------- RoPE tables: cos/sin[s][i], i in [0,64) ----------------
__global__ __launch_bounds__(256) void rope_tables(float* __restrict__ cosT,
                                                   float* __restrict__ sinT) {
  int idx = blockIdx.x * 256 + threadIdx.x;  // S*64 entries
  int s = idx >> 6, i = idx & 63;
  float invf = powf(10000.0f, -(float)i * (1.0f / 64.0f));
  float a = (float)s * invf;
  cosT[idx] = cosf(a);
  sinT[idx] = sinf(a);
}

// ---------------- GEMM: C[M][N] = A[M][K] * Bt[N][K]^T, bf16 in, f32 acc ----------------
template <typename OutT>
__global__ __launch_bounds__(256) void gemm_bt(const unsigned short* __restrict__ A,
                                               const unsigned short* __restrict__ Bt,
                                               OutT* __restrict__ C,
                                               int Mdim, int Ndim, int Kdim) {
  __shared__ unsigned short As[128 * 32];
  __shared__ unsigned short Bs[128 * 32];
  const int ntn = Ndim >> 7;
  const int tm = (blockIdx.x / ntn) << 7;
  const int tn = (blockIdx.x % ntn) << 7;
  const int tid = threadIdx.x;
  const int w = tid >> 6, l = tid & 63;
  const int g = l >> 4, cc = l & 15;
  const int wm = (w >> 1) << 6;
  const int wn = (w & 1) << 6;
  f32x4 acc[4][4] = {};

  const int srow = (w << 5) + (l >> 2);
  const int scol = (l & 3) << 3;
  const unsigned short* ga = A + (long long)(tm + srow) * Kdim + scol;
  const unsigned short* gb = Bt + (long long)(tn + srow) * Kdim + scol;
  unsigned short* la0 = As + ((w << 5) << 5);
  unsigned short* la1 = As + (((w << 5) + 16) << 5);
  unsigned short* lb0 = Bs + ((w << 5) << 5);
  unsigned short* lb1 = Bs + (((w << 5) + 16) << 5);

  const int nk = Kdim >> 5;
  for (int kt = 0; kt < nk; ++kt) {
    __syncthreads();
    async16(ga, la0);
    async16(ga + 16 * Kdim, la1);
    async16(gb, lb0);
    async16(gb + 16 * Kdim, lb1);
    ga += 32; gb += 32;
    __syncthreads();

    bf16x8 af[4], bfr[4];
#pragma unroll
    for (int i = 0; i < 4; ++i)
      af[i] = *(const bf16x8*)(As + ((wm + (i << 4) + cc) << 5) + (g << 3));
#pragma unroll
    for (int j = 0; j < 4; ++j)
      bfr[j] = *(const bf16x8*)(Bs + ((wn + (j << 4) + cc) << 5) + (g << 3));
#pragma unroll
    for (int i = 0; i < 4; ++i)
#pragma unroll
      for (int j = 0; j < 4; ++j)
        acc[i][j] = MFMA16(af[i], bfr[j], acc[i][j]);
  }

#pragma unroll
  for (int i = 0; i < 4; ++i)
#pragma unroll
    for (int j = 0; j < 4; ++j)
#pragma unroll
      for (int p = 0; p < 4; ++p) {
        int row = tm + wm + (i << 4) + (g << 2) + p;
        int col = tn + wn + (j << 4) + cc;
        store_c(&C[(long long)row * Ndim + col], acc[i][j][p]);
      }
}

// ---------------- split qkv -> Q (pre-scaled), K (RoPE, [B,H,S,D]) and Vt ([B,H,D,S]) ----------------
__global__ __launch_bounds__(256) void split_rope(const unsigned short* __restrict__ qkv,
                                                  const float* __restrict__ cosT,
                                                  const float* __restrict__ sinT,
                                                  unsigned short* __restrict__ Qb,
                                                  unsigned short* __restrict__ Kb,
                                                  unsigned short* __restrict__ Vt) {
  __shared__ unsigned short vtile[32][128];
  const int bid = blockIdx.x;
  const int st = bid & 63;
  const int h = (bid >> 6) & 15;
  const int b = bid >> 10;
  const int s0 = st << 5;
  const int t = threadIdx.x;
  const int d = t & 127;
  const int sl0 = t >> 7;
  const int dh = d & 63;
  const float sgn = (d < 64) ? -1.0f : 1.0f;
  const float qscale = 0.08838834764831845f;  // 1/sqrt(128), baked into Q
#pragma unroll
  for (int it = 0; it < 16; ++it) {
    const int sl = sl0 + (it << 1);
    const int s = s0 + sl;
    const long long rb = ((long long)(b * S_LEN + s)) * N3 + h * HD;
    const float cv = cosT[(s << 6) + dh];
    const float sv = sinT[(s << 6) + dh];
    float qv = bf2f(qkv[rb + d]);
    float qo = bf2f(qkv[rb + (d ^ 64)]);
    float kv = bf2f(qkv[rb + HID_DIM + d]);
    float ko = bf2f(qkv[rb + HID_DIM + (d ^ 64)]);
    const long long ob = ((long long)((b * NH + h) * S_LEN + s)) * HD + d;
    Qb[ob] = f2bf((qv * cv + sgn * qo * sv) * qscale);
    Kb[ob] = f2bf(kv * cv + sgn * ko * sv);
    vtile[sl][d] = qkv[rb + 2 * HID_DIM + d];
  }
  __syncthreads();
  const int dr = t >> 1;
  const int sh = (t & 1) << 4;
  unsigned short tv[16];
#pragma unroll
  for (int j = 0; j < 16; ++j) tv[j] = vtile[sh + j][dr];
  uint4 u0, u1;
  u0.x = (unsigned)tv[0] | ((unsigned)tv[1] << 16);
  u0.y = (unsigned)tv[2] | ((unsigned)tv[3] << 16);
  u0.z = (unsigned)tv[4] | ((unsigned)tv[5] << 16);
  u0.w = (unsigned)tv[6] | ((unsigned)tv[7] << 16);
  u1.x = (unsigned)tv[8] | ((unsigned)tv[9] << 16);
  u1.y = (unsigned)tv[10] | ((unsigned)tv[11] << 16);
  u1.z = (unsigned)tv[12] | ((unsigned)tv[13] << 16);
  u1.w = (unsigned)tv[14] | ((unsigned)tv[15] << 16);
  const long long vb = ((long long)((b * NH + h) * HD + dr)) * S_LEN + s0 + sh;
  *(uint4*)(Vt + vb) = u0;
  *(uint4*)(Vt + vb + 8) = u1;
}

// ---------------- flash attention: swapped-operand 32x32 MFMA, in-register softmax ----------------
// Block: 4 waves x 32 q-rows = 128 q rows. Grid: 16 qt x 32 bh = 512 blocks, balanced dispatch.
// S^T = mfma(K_frag, Q_frag): lane holds 32 kv-values of P for q = lane&31 -> softmax is
// in-lane + one shfl_xor(32). P feeds PV (O^T = mfma(V^T, P^T)) straight from registers.
__global__ __launch_bounds__(256) void flash_attn(const unsigned short* __restrict__ Qg,
                                                  const unsigned short* __restrict__ Kg,
                                                  const unsigned short* __restrict__ Vt,
                                                  unsigned short* __restrict__ Ob) {
  __shared__ unsigned short smem[32768];  // 64KB: K dbuf 2x16KB | V dbuf 2x16KB; epilogue overlay
  const int id = blockIdx.x;
  const int bh = id & 31;
  const int qtr = (id >> 5) & 7;
  const int qt = (id >> 8) ? qtr : 15 - qtr;   // first 256 blocks = heavy halves
  const int Q0 = qt << 7;
  const int b = bh >> 4, h = bh & 15;
  const long long base = (long long)bh * (S_LEN * HD);
  const int tid = threadIdx.x, w = tid >> 6, l = tid & 63;
  const int hi = l >> 5, q = l & 31;
  const int q0w = Q0 + (w << 5);
  const int g = l >> 4, c = l & 15;  // staging helpers

  // Q fragments (B operand): col = q0w+q, k = d = 16s + 8*hi + j
  bf16x8 qf[8];
  {
    const unsigned short* qp = Qg + base + (long long)(q0w + q) * HD + (hi << 3);
#pragma unroll
    for (int s = 0; s < 8; ++s) qf[s] = *(const bf16x8*)(qp + (s << 4));
  }

  f32x16 oacc[4] = {};  // O^T[d=32db+cr(j)][q], cr(j)=(j&3)+8*(j>>2)+4*hi
  float m = -1e30f, lsum = 0.f;

  const int nt = (qt << 1) + 2;

  auto STAGE = [&](int kv0, int buf) {
    unsigned short* ks = smem + buf * 8192;
    unsigned short* vs = smem + 16384 + buf * 8192;
#pragma unroll
    for (int j = 0; j < 4; ++j) {
      int row = (w << 4) + (j << 2) + g;
      int chunk = c ^ (row & 7);
      async16(Kg + base + (long long)(kv0 + row) * HD + (chunk << 3),
              ks + (((w << 4) + (j << 2)) << 7));
    }
#pragma unroll
    for (int j = 0; j < 4; ++j) {
      int dr = (w << 5) + (j << 3) + (l >> 3);
      int chunk = (l & 7) ^ (dr & 7);
      async16(Vt + base + (long long)dr * S_LEN + kv0 + (chunk << 3),
              vs + (((w << 5) + (j << 3)) << 6));
    }
  };

  STAGE(0, 0);
  __syncthreads();  // implicit vmcnt(0): tile 0 ready

  int cur = 0;
  for (int t = 0; t < nt; ++t) {
    const int kv0 = t << 6;
    if (t + 1 < nt) STAGE((t + 1) << 6, cur ^ 1);

    if (kv0 < q0w + 32) {  // wave-uniform causal skip
      const unsigned short* ks = smem + cur * 8192;
      const unsigned short* vs = smem + 16384 + cur * 8192;

      // S^T[kv][q] = K Q^T : 16 MFMAs (2 kv-halves x 8 d-slices)
      f32x16 sa[2] = {};
#pragma unroll
      for (int h2 = 0; h2 < 2; ++h2) {
        const char* kb = (const char*)ks + (((h2 << 5) + q) << 8);
        const int r7 = q & 7;
#pragma unroll
        for (int s = 0; s < 8; ++s) {
          bf16x8 kf = *(const bf16x8*)(kb + ((((s << 1) + hi) ^ r7) << 4));
          sa[h2] = MFMA32(kf, qf[s], sa[h2]);
        }
      }

      if (kv0 + 63 > q0w) {  // diagonal-overlap tiles: mask kv > q
        const int qq = q0w + q;
#pragma unroll
        for (int h2 = 0; h2 < 2; ++h2)
#pragma unroll
          for (int j = 0; j < 16; ++j) {
            int kv = kv0 + (h2 << 5) + (j & 3) + ((j >> 2) << 3) + (hi << 2);
            if (kv > qq) sa[h2][j] = -1e30f;
          }
      }

      // online softmax: in-lane over 32 values + one cross-half swap
      float tmax = -1e30f;
#pragma unroll
      for (int h2 = 0; h2 < 2; ++h2)
#pragma unroll
        for (int j = 0; j < 16; ++j) tmax = fmaxf(tmax, sa[h2][j]);
      tmax = fmaxf(tmax, __shfl_xor(tmax, 32));
      float mn = fmaxf(m, tmax);
      float fsc = __expf(m - mn);
      m = mn;
      float ps = 0.f;
#pragma unroll
      for (int h2 = 0; h2 < 2; ++h2)
#pragma unroll
        for (int j = 0; j < 16; ++j) {
          float pv = __expf(sa[h2][j] - mn);
          sa[h2][j] = pv;
          ps += pv;
        }
      ps += __shfl_xor(ps, 32);
      lsum = lsum * fsc + ps;
#pragma unroll
      for (int db = 0; db < 4; ++db)
#pragma unroll
        for (int j = 0; j < 16; ++j) oacc[db][j] *= fsc;

      // pack P to bf16 pairs + cross-half exchange -> PV B-fragments (P^T)
      unsigned up[2][8], wp[2][8];
#pragma unroll
      for (int h2 = 0; h2 < 2; ++h2)
#pragma unroll
        for (int k = 0; k < 8; ++k)
          up[h2][k] = packbf2(sa[h2][2 * k], sa[h2][2 * k + 1]);
#pragma unroll
      for (int h2 = 0; h2 < 2; ++h2)
#pragma unroll
        for (int k = 0; k < 8; ++k)
          wp[h2][k] = __shfl_xor((int)up[h2][k], 32);
      union Frag { unsigned u[4]; bf16x8 v; } pf[4];
#pragma unroll
      for (int s = 0; s < 4; ++s) {
        int h2 = s >> 1, q4 = (s & 1) << 2;
        pf[s].u[0] = hi ? wp[h2][q4 + 2] : up[h2][q4];
        pf[s].u[1] = hi ? wp[h2][q4 + 3] : up[h2][q4 + 1];
        pf[s].u[2] = hi ? up[h2][q4 + 2] : wp[h2][q4];
        pf[s].u[3] = hi ? up[h2][q4 + 3] : wp[h2][q4 + 1];
      }

      // O^T += V^T P^T : 16 MFMAs (4 d-blocks x 4 kv-slices)
#pragma unroll
      for (int db = 0; db < 4; ++db) {
        const char* vb = (const char*)vs + (((db << 5) + q) << 7);
        const int d7 = q & 7;
#pragma unroll
        for (int s = 0; s < 4; ++s) {
          bf16x8 vf = *(const bf16x8*)(vb + ((((s << 1) + hi) ^ d7) << 4));
          oacc[db] = MFMA32(vf, pf[s].v, oacc[db]);
        }
      }
    }

    __syncthreads();  // drains prefetch + guards buffer reuse
    cur ^= 1;
  }

  // epilogue: divide by lsum, transpose via LDS overlay, coalesced 16B stores
  const float rl = 1.0f / lsum;
#pragma unroll
  for (int db = 0; db < 4; ++db)
#pragma unroll
    for (int jg = 0; jg < 4; ++jg) {
      int d = (db << 5) + (jg << 3) + (hi << 2);
      unsigned v0 = packbf2(oacc[db][4 * jg] * rl, oacc[db][4 * jg + 1] * rl);
      unsigned v1 = packbf2(oacc[db][4 * jg + 2] * rl, oacc[db][4 * jg + 3] * rl);
      *(uint2*)(smem + (((w << 5) + q) << 7) + d) = make_uint2(v0, v1);
    }
  __syncthreads();
  {
    const int qr = tid >> 1;
    const int dh = (tid & 1) << 6;
    const uint4* src = (const uint4*)(smem + (qr << 7) + dh);
    uint4* dst = (uint4*)(Ob + (long long)((b << 11) + Q0 + qr) * HID_DIM + (h << 7) + dh);
#pragma unroll
    for (int cc2 = 0; cc2 < 8; ++cc2) dst[cc2] = src[cc2];
  }
}

// ---------------- launch ----------------
extern "C" void kernel_launch(void* const* d_in, const int* in_sizes, int n_in,
                              void* d_out, int out_size, void* d_ws, size_t ws_size,
                              hipStream_t stream) {
  (void)in_sizes; (void)n_in; (void)out_size; (void)ws_size;
  const float* x = (const float*)d_in[0];
  const float* w_qkv = (const float*)d_in[1];
  const float* w_out = (const float*)d_in[2];
  float* out = (float*)d_out;
  char* ws = (char*)d_ws;

  unsigned short* xb    = (unsigned short*)(ws);              // 16 MB  [4096][2048]
  unsigned short* wqkvT = (unsigned short*)(ws + 16777216);   // 24 MB  [6144][2048]
  unsigned short* woutT = (unsigned short*)(ws + 41943040);   //  8 MB  [2048][2048]
  unsigned short* qkv   = (unsigned short*)(ws + 50331648);   // 48 MB  [4096][6144] (reused as O)
  unsigned short* Qb    = (unsigned short*)(ws + 100663296);  // 16 MB  [B,H,S,D]
  unsigned short* Kb    = (unsigned short*)(ws + 117440512);  // 16 MB  [B,H,S,D]
  unsigned short* Vt    = (unsigned short*)(ws + 134217728);  // 16 MB  [B,H,D,S]
  float* cosT = (float*)(ws + 150994944);                     // 0.5 MB [S][64]
  float* sinT = (float*)(ws + 151519232);                     // 0.5 MB
  unsigned short* Ob = qkv;

  cast_bf16<<<8192, 256, 0, stream>>>((const float4*)x, (ushort4*)xb);
  transpose_cast<<<12288, 256, 0, stream>>>(w_qkv, wqkvT, 2048, 6144);
  transpose_cast<<<4096, 256, 0, stream>>>(w_out, woutT, 2048, 2048);
  rope_tables<<<512, 256, 0, stream>>>(cosT, sinT);
  gemm_bt<unsigned short><<<1536, 256, 0, stream>>>(xb, wqkvT, qkv, 4096, 6144, 2048);
  split_rope<<<2048, 256, 0, stream>>>(qkv, cosT, sinT, Qb, Kb, Vt);
  flash_attn<<<512, 256, 0, stream>>>(Qb, Kb, Vt, Ob);
  gemm_bt<float><<<512, 256, 0, stream>>>(Ob, woutT, out, 4096, 2048, 2048);
}

// Round 4
// 297.174 us; speedup vs baseline: 1.4302x; 1.1182x over previous
//
#include <hip/hip_runtime.h>
#include <hip/hip_bf16.h>

// Problem constants (B=2, S=2048, HID=2048, H=16, D=128)
#define S_LEN 2048
#define HID_DIM 2048
#define NH 16
#define HD 128
#define N3 6144

typedef __bf16 bf16x8 __attribute__((ext_vector_type(8)));
typedef float f32x4 __attribute__((ext_vector_type(4)));
typedef float f32x16 __attribute__((ext_vector_type(16)));

#define MFMA16(a, b, c) __builtin_amdgcn_mfma_f32_16x16x32_bf16(a, b, c, 0, 0, 0)
#define MFMA32(a, b, c) __builtin_amdgcn_mfma_f32_32x32x16_bf16(a, b, c, 0, 0, 0)

__device__ __forceinline__ unsigned short f2bf(float f) {
  union { float f; unsigned u; } v; v.f = f;
  return (unsigned short)((v.u + 0x7fffu + ((v.u >> 16) & 1u)) >> 16);
}
__device__ __forceinline__ float bf2f(unsigned short h) {
  union { unsigned u; float f; } v; v.u = ((unsigned)h) << 16; return v.f;
}
__device__ __forceinline__ unsigned packbf2(float lo, float hi) {
  union { __hip_bfloat162 h2; unsigned u; } cv;
  cv.h2 = __float22bfloat162_rn(make_float2(lo, hi));
  return cv.u;
}
__device__ __forceinline__ void store_c(float* p, float v) { *p = v; }
__device__ __forceinline__ void store_c(unsigned short* p, float v) { *p = f2bf(v); }

// async global->LDS, 16B per lane; LDS dest = wave-uniform base + lane*16
__device__ __forceinline__ void async16(const void* g, void* l) {
  __builtin_amdgcn_global_load_lds((const __attribute__((address_space(1))) unsigned int*)g,
                                   (__attribute__((address_space(3))) unsigned int*)l,
                                   16, 0, 0);
}

// ---------------- elementwise cast f32 -> bf16 (vectorized) ----------------
__global__ __launch_bounds__(256) void cast_bf16(const float4* __restrict__ src,
                                                 ushort4* __restrict__ dst) {
  int i = blockIdx.x * 256 + threadIdx.x;
  float4 v = src[i];
  ushort4 o;
  o.x = f2bf(v.x); o.y = f2bf(v.y); o.z = f2bf(v.z); o.w = f2bf(v.w);
  dst[i] = o;
}

// ---------------- transpose + cast: src[R][C] f32 -> dst[C][R] bf16 ----------------
__global__ __launch_bounds__(256) void transpose_cast(const float* __restrict__ src,
                                                      unsigned short* __restrict__ dst,
                                                      int R, int Ccols) {
  __shared__ float t[32][33];
  int ct = Ccols >> 5;
  int bx = blockIdx.x % ct, by = blockIdx.x / ct;
  int c0 = bx << 5, r0 = by << 5;
  int lx = threadIdx.x & 31, ly = threadIdx.x >> 5;
#pragma unroll
  for (int i = 0; i < 32; i += 8)
    t[ly + i][lx] = src[(long long)(r0 + ly + i) * Ccols + c0 + lx];
  __syncthreads();
#pragma unroll
  for (int i = 0; i < 32; i += 8)
    dst[(long long)(c0 + ly + i) * R + r0 + lx] = f2bf(t[lx][ly + i]);
}

// ---------------- RoPE tables: cos/sin[s][i], i in [0,64) ----------------
__global__ __launch_bounds__(256) void rope_tables(float* __restrict__ cosT,
                                                   float* __restrict__ sinT) {
  int idx = blockIdx.x * 256 + threadIdx.x;  // S*64 entries
  int s = idx >> 6, i = idx & 63;
  float invf = powf(10000.0f, -(float)i * (1.0f / 64.0f));
  float a = (float)s * invf;
  cosT[idx] = cosf(a);
  sinT[idx] = sinf(a);
}

// ---------------- pipelined GEMM: C[M][N] = A[M][K] * Bt[N][K]^T ----------------
// BK=64, 8 waves (WM x WN grid), double-buffered LDS, 4-phase K-group:
//   p0: ds_read a(low)+b(all), stage A(t+1); p1: stage B(t+1); p2: ds_read a(high); p3: drain.
// Raw s_barrier (no vmcnt drain mid-group); single vmcnt(0) per group, covered by 64 MFMAs.
// T2: LDS chunk-swizzle via pre-swizzled global source; T5: setprio around MFMA clusters.
template <int BM, int BN, int WM, int WN, typename OutT>
__global__ __launch_bounds__(512) void gemm_pipe(const unsigned short* __restrict__ A,
                                                 const unsigned short* __restrict__ Bt,
                                                 OutT* __restrict__ C,
                                                 int Mdim, int Ndim, int Kdim) {
  constexpr int WTM = BM / WM, WTN = BN / WN;
  constexpr int MREP = WTM / 16, NREP = WTN / 16;
  constexpr int AEL = BM * 64;     // elements per A K-tile (BK=64)
  constexpr int BEL = BN * 64;
  constexpr int BUFE = AEL + BEL;  // elements per buffer
  __shared__ unsigned short smem[2 * BUFE];

  const int ntn = Ndim / BN;
  const int nwg = (Mdim / BM) * ntn;
  int bid = blockIdx.x;
  bid = (bid & 7) * (nwg >> 3) + (bid >> 3);  // XCD swizzle (nwg % 8 == 0)
  const int tm = (bid / ntn) * BM;
  const int tn = (bid % ntn) * BN;

  const int tid = threadIdx.x;
  const int w = tid >> 6, l = tid & 63;
  const int g = l >> 4, cc = l & 15;
  const int wm = w / WN, wn = w % WN;

  // staging: 512 threads x 16B = 64 rows x 64k per instr; source chunk pre-swizzled
  const int srow = tid >> 3;                 // 0..63
  const int schunk = (tid & 7) ^ (srow & 7);
  const unsigned short* gA = A + (long long)(tm + srow) * Kdim + schunk * 8;
  const unsigned short* gB = Bt + (long long)(tn + srow) * Kdim + schunk * 8;

  // swizzled read chunk offsets (elements): phys chunk = (ks*4+g) ^ (row&7), row&7 == cc&7
  const int ch0 = ((g) ^ (cc & 7)) << 3;
  const int ch1 = ((4 + g) ^ (cc & 7)) << 3;

  f32x4 acc[MREP][NREP] = {};
  bf16x8 a[MREP / 2][2], b[NREP][2];

  const int nk = Kdim >> 6;

  // prologue: stage K-tile 0 into buf 0
#pragma unroll
  for (int s = 0; s < BM / 64; ++s)
    async16(gA + (long long)s * 64 * Kdim, smem + s * 4096 + w * 512);
#pragma unroll
  for (int s = 0; s < BN / 64; ++s)
    async16(gB + (long long)s * 64 * Kdim, smem + AEL + s * 4096 + w * 512);
  asm volatile("s_waitcnt vmcnt(0)" ::: "memory");
  __builtin_amdgcn_s_barrier();

  for (int kt = 0; kt < nk; ++kt) {
    const int buf = kt & 1;
    const unsigned short* Ab = smem + buf * BUFE + (wm * WTM) * 64;
    const unsigned short* Bb = smem + buf * BUFE + AEL + (wn * WTN) * 64;
    const long long kb = (long long)(kt + 1) << 6;
    unsigned short* nb = smem + (buf ^ 1) * BUFE;

    // ---- phase 0: read a(low half) + b(all); stage next A
#pragma unroll
    for (int i = 0; i < MREP / 2; ++i) {
      const int r = (i * 16 + cc) << 6;
      a[i][0] = *(const bf16x8*)(Ab + r + ch0);
      a[i][1] = *(const bf16x8*)(Ab + r + ch1);
    }
#pragma unroll
    for (int j = 0; j < NREP; ++j) {
      const int r = (j * 16 + cc) << 6;
      b[j][0] = *(const bf16x8*)(Bb + r + ch0);
      b[j][1] = *(const bf16x8*)(Bb + r + ch1);
    }
    if (kt + 1 < nk) {
#pragma unroll
      for (int s = 0; s < BM / 64; ++s)
        async16(gA + (long long)s * 64 * Kdim + kb, nb + s * 4096 + w * 512);
    }
    __builtin_amdgcn_s_barrier();
    __builtin_amdgcn_s_setprio(1);
#pragma unroll
    for (int i = 0; i < MREP / 2; ++i)
#pragma unroll
      for (int j = 0; j < NREP / 2; ++j) {
        acc[i][j] = MFMA16(a[i][0], b[j][0], acc[i][j]);
        acc[i][j] = MFMA16(a[i][1], b[j][1], acc[i][j]);
      }
    __builtin_amdgcn_s_setprio(0);
    __builtin_amdgcn_s_barrier();

    // ---- phase 1: stage next B
    if (kt + 1 < nk) {
#pragma unroll
      for (int s = 0; s < BN / 64; ++s)
        async16(gB + (long long)s * 64 * Kdim + kb, nb + AEL + s * 4096 + w * 512);
    }
    __builtin_amdgcn_s_barrier();
    __builtin_amdgcn_s_setprio(1);
#pragma unroll
    for (int i = 0; i < MREP / 2; ++i)
#pragma unroll
      for (int j = 0; j < NREP / 2; ++j) {
        acc[i][NREP / 2 + j] = MFMA16(a[i][0], b[NREP / 2 + j][0], acc[i][NREP / 2 + j]);
        acc[i][NREP / 2 + j] = MFMA16(a[i][1], b[NREP / 2 + j][1], acc[i][NREP / 2 + j]);
      }
    __builtin_amdgcn_s_setprio(0);
    __builtin_amdgcn_s_barrier();

    // ---- phase 2: read a(high half)
#pragma unroll
    for (int i = 0; i < MREP / 2; ++i) {
      const int r = ((WTM / 2) + i * 16 + cc) << 6;
      a[i][0] = *(const bf16x8*)(Ab + r + ch0);
      a[i][1] = *(const bf16x8*)(Ab + r + ch1);
    }
    __builtin_amdgcn_s_barrier();
    __builtin_amdgcn_s_setprio(1);
#pragma unroll
    for (int i = 0; i < MREP / 2; ++i)
#pragma unroll
      for (int j = 0; j < NREP / 2; ++j) {
        acc[MREP / 2 + i][j] = MFMA16(a[i][0], b[j][0], acc[MREP / 2 + i][j]);
        acc[MREP / 2 + i][j] = MFMA16(a[i][1], b[j][1], acc[MREP / 2 + i][j]);
      }
    __builtin_amdgcn_s_setprio(0);
    __builtin_amdgcn_s_barrier();

    // ---- phase 3: remaining quadrant; group-end drain
    __builtin_amdgcn_s_setprio(1);
#pragma unroll
    for (int i = 0; i < MREP / 2; ++i)
#pragma unroll
      for (int j = 0; j < NREP / 2; ++j) {
        acc[MREP / 2 + i][NREP / 2 + j] =
            MFMA16(a[i][0], b[NREP / 2 + j][0], acc[MREP / 2 + i][NREP / 2 + j]);
        acc[MREP / 2 + i][NREP / 2 + j] =
            MFMA16(a[i][1], b[NREP / 2 + j][1], acc[MREP / 2 + i][NREP / 2 + j]);
      }
    __builtin_amdgcn_s_setprio(0);
    asm volatile("s_waitcnt vmcnt(0)" ::: "memory");
    __builtin_amdgcn_s_barrier();
  }

  // epilogue (acc[i][j] row offset = i*16 uniformly, col offset = j*16)
  const int crow0 = tm + wm * WTM;
  const int ccol0 = tn + wn * WTN;
#pragma unroll
  for (int i = 0; i < MREP; ++i)
#pragma unroll
    for (int j = 0; j < NREP; ++j)
#pragma unroll
      for (int p = 0; p < 4; ++p) {
        int row = crow0 + i * 16 + (g << 2) + p;
        int col = ccol0 + j * 16 + cc;
        store_c(&C[(long long)row * Ndim + col], acc[i][j][p]);
      }
}

// ---------------- split qkv -> Q (pre-scaled), K (RoPE, [B,H,S,D]) and Vt ([B,H,D,S]) ----------------
__global__ __launch_bounds__(256) void split_rope(const unsigned short* __restrict__ qkv,
                                                  const float* __restrict__ cosT,
                                                  const float* __restrict__ sinT,
                                                  unsigned short* __restrict__ Qb,
                                                  unsigned short* __restrict__ Kb,
                                                  unsigned short* __restrict__ Vt) {
  __shared__ unsigned short vtile[32][128];
  const int bid = blockIdx.x;
  const int st = bid & 63;
  const int h = (bid >> 6) & 15;
  const int b = bid >> 10;
  const int s0 = st << 5;
  const int t = threadIdx.x;
  const int d = t & 127;
  const int sl0 = t >> 7;
  const int dh = d & 63;
  const float sgn = (d < 64) ? -1.0f : 1.0f;
  const float qscale = 0.08838834764831845f;  // 1/sqrt(128), baked into Q
#pragma unroll
  for (int it = 0; it < 16; ++it) {
    const int sl = sl0 + (it << 1);
    const int s = s0 + sl;
    const long long rb = ((long long)(b * S_LEN + s)) * N3 + h * HD;
    const float cv = cosT[(s << 6) + dh];
    const float sv = sinT[(s << 6) + dh];
    float qv = bf2f(qkv[rb + d]);
    float qo = bf2f(qkv[rb + (d ^ 64)]);
    float kv = bf2f(qkv[rb + HID_DIM + d]);
    float ko = bf2f(qkv[rb + HID_DIM + (d ^ 64)]);
    const long long ob = ((long long)((b * NH + h) * S_LEN + s)) * HD + d;
    Qb[ob] = f2bf((qv * cv + sgn * qo * sv) * qscale);
    Kb[ob] = f2bf(kv * cv + sgn * ko * sv);
    vtile[sl][d] = qkv[rb + 2 * HID_DIM + d];
  }
  __syncthreads();
  const int dr = t >> 1;
  const int sh = (t & 1) << 4;
  unsigned short tv[16];
#pragma unroll
  for (int j = 0; j < 16; ++j) tv[j] = vtile[sh + j][dr];
  uint4 u0, u1;
  u0.x = (unsigned)tv[0] | ((unsigned)tv[1] << 16);
  u0.y = (unsigned)tv[2] | ((unsigned)tv[3] << 16);
  u0.z = (unsigned)tv[4] | ((unsigned)tv[5] << 16);
  u0.w = (unsigned)tv[6] | ((unsigned)tv[7] << 16);
  u1.x = (unsigned)tv[8] | ((unsigned)tv[9] << 16);
  u1.y = (unsigned)tv[10] | ((unsigned)tv[11] << 16);
  u1.z = (unsigned)tv[12] | ((unsigned)tv[13] << 16);
  u1.w = (unsigned)tv[14] | ((unsigned)tv[15] << 16);
  const long long vb = ((long long)((b * NH + h) * HD + dr)) * S_LEN + s0 + sh;
  *(uint4*)(Vt + vb) = u0;
  *(uint4*)(Vt + vb + 8) = u1;
}

// ---------------- flash attention: swapped-operand 32x32 MFMA, in-register softmax ----------------
__global__ __launch_bounds__(256) void flash_attn(const unsigned short* __restrict__ Qg,
                                                  const unsigned short* __restrict__ Kg,
                                                  const unsigned short* __restrict__ Vt,
                                                  unsigned short* __restrict__ Ob) {
  __shared__ unsigned short smem[32768];  // 64KB: K dbuf 2x16KB | V dbuf 2x16KB; epilogue overlay
  const int id = blockIdx.x;
  const int bh = id & 31;
  const int qtr = (id >> 5) & 7;
  const int qt = (id >> 8) ? qtr : 15 - qtr;   // first 256 blocks = heavy halves
  const int Q0 = qt << 7;
  const int b = bh >> 4, h = bh & 15;
  const long long base = (long long)bh * (S_LEN * HD);
  const int tid = threadIdx.x, w = tid >> 6, l = tid & 63;
  const int hi = l >> 5, q = l & 31;
  const int q0w = Q0 + (w << 5);
  const int g = l >> 4, c = l & 15;  // staging helpers

  // Q fragments (B operand): col = q0w+q, k = d = 16s + 8*hi + j
  bf16x8 qf[8];
  {
    const unsigned short* qp = Qg + base + (long long)(q0w + q) * HD + (hi << 3);
#pragma unroll
    for (int s = 0; s < 8; ++s) qf[s] = *(const bf16x8*)(qp + (s << 4));
  }

  f32x16 oacc[4] = {};  // O^T[d=32db+cr(j)][q], cr(j)=(j&3)+8*(j>>2)+4*hi
  float m = -1e30f, lsum = 0.f;

  const int nt = (qt << 1) + 2;

  auto STAGE = [&](int kv0, int buf) {
    unsigned short* ks = smem + buf * 8192;
    unsigned short* vs = smem + 16384 + buf * 8192;
#pragma unroll
    for (int j = 0; j < 4; ++j) {
      int row = (w << 4) + (j << 2) + g;
      int chunk = c ^ (row & 7);
      async16(Kg + base + (long long)(kv0 + row) * HD + (chunk << 3),
              ks + (((w << 4) + (j << 2)) << 7));
    }
#pragma unroll
    for (int j = 0; j < 4; ++j) {
      int dr = (w << 5) + (j << 3) + (l >> 3);
      int chunk = (l & 7) ^ (dr & 7);
      async16(Vt + base + (long long)dr * S_LEN + kv0 + (chunk << 3),
              vs + (((w << 5) + (j << 3)) << 6));
    }
  };

  STAGE(0, 0);
  __syncthreads();  // implicit vmcnt(0): tile 0 ready

  int cur = 0;
  for (int t = 0; t < nt; ++t) {
    const int kv0 = t << 6;
    if (t + 1 < nt) STAGE((t + 1) << 6, cur ^ 1);

    if (kv0 < q0w + 32) {  // wave-uniform causal skip
      const unsigned short* ks = smem + cur * 8192;
      const unsigned short* vs = smem + 16384 + cur * 8192;

      // S^T[kv][q] = K Q^T : 16 MFMAs (2 kv-halves x 8 d-slices)
      f32x16 sa[2] = {};
#pragma unroll
      for (int h2 = 0; h2 < 2; ++h2) {
        const char* kb = (const char*)ks + (((h2 << 5) + q) << 8);
        const int r7 = q & 7;
#pragma unroll
        for (int s = 0; s < 8; ++s) {
          bf16x8 kf = *(const bf16x8*)(kb + ((((s << 1) + hi) ^ r7) << 4));
          sa[h2] = MFMA32(kf, qf[s], sa[h2]);
        }
      }

      if (kv0 + 63 > q0w) {  // diagonal-overlap tiles: mask kv > q
        const int qq = q0w + q;
#pragma unroll
        for (int h2 = 0; h2 < 2; ++h2)
#pragma unroll
          for (int j = 0; j < 16; ++j) {
            int kv = kv0 + (h2 << 5) + (j & 3) + ((j >> 2) << 3) + (hi << 2);
            if (kv > qq) sa[h2][j] = -1e30f;
          }
      }

      // online softmax: in-lane over 32 values + one cross-half swap
      float tmax = -1e30f;
#pragma unroll
      for (int h2 = 0; h2 < 2; ++h2)
#pragma unroll
        for (int j = 0; j < 16; ++j) tmax = fmaxf(tmax, sa[h2][j]);
      tmax = fmaxf(tmax, __shfl_xor(tmax, 32));
      float mn = fmaxf(m, tmax);
      float fsc = __expf(m - mn);
      m = mn;
      float ps = 0.f;
#pragma unroll
      for (int h2 = 0; h2 < 2; ++h2)
#pragma unroll
        for (int j = 0; j < 16; ++j) {
          float pv = __expf(sa[h2][j] - mn);
          sa[h2][j] = pv;
          ps += pv;
        }
      ps += __shfl_xor(ps, 32);
      lsum = lsum * fsc + ps;
#pragma unroll
      for (int db = 0; db < 4; ++db)
#pragma unroll
        for (int j = 0; j < 16; ++j) oacc[db][j] *= fsc;

      // pack P to bf16 pairs + cross-half exchange -> PV B-fragments (P^T)
      unsigned up[2][8], wp[2][8];
#pragma unroll
      for (int h2 = 0; h2 < 2; ++h2)
#pragma unroll
        for (int k = 0; k < 8; ++k)
          up[h2][k] = packbf2(sa[h2][2 * k], sa[h2][2 * k + 1]);
#pragma unroll
      for (int h2 = 0; h2 < 2; ++h2)
#pragma unroll
        for (int k = 0; k < 8; ++k)
          wp[h2][k] = __shfl_xor((int)up[h2][k], 32);
      union Frag { unsigned u[4]; bf16x8 v; } pf[4];
#pragma unroll
      for (int s = 0; s < 4; ++s) {
        int h2 = s >> 1, q4 = (s & 1) << 2;
        pf[s].u[0] = hi ? wp[h2][q4 + 2] : up[h2][q4];
        pf[s].u[1] = hi ? wp[h2][q4 + 3] : up[h2][q4 + 1];
        pf[s].u[2] = hi ? up[h2][q4 + 2] : wp[h2][q4];
        pf[s].u[3] = hi ? up[h2][q4 + 3] : wp[h2][q4 + 1];
      }

      // O^T += V^T P^T : 16 MFMAs (4 d-blocks x 4 kv-slices)
#pragma unroll
      for (int db = 0; db < 4; ++db) {
        const char* vb = (const char*)vs + (((db << 5) + q) << 7);
        const int d7 = q & 7;
#pragma unroll
        for (int s = 0; s < 4; ++s) {
          bf16x8 vf = *(const bf16x8*)(vb + ((((s << 1) + hi) ^ d7) << 4));
          oacc[db] = MFMA32(vf, pf[s].v, oacc[db]);
        }
      }
    }

    __syncthreads();  // drains prefetch + guards buffer reuse
    cur ^= 1;
  }

  // epilogue: divide by lsum, transpose via LDS overlay, coalesced 16B stores
  const float rl = 1.0f / lsum;
#pragma unroll
  for (int db = 0; db < 4; ++db)
#pragma unroll
    for (int jg = 0; jg < 4; ++jg) {
      int d = (db << 5) + (jg << 3) + (hi << 2);
      unsigned v0 = packbf2(oacc[db][4 * jg] * rl, oacc[db][4 * jg + 1] * rl);
      unsigned v1 = packbf2(oacc[db][4 * jg + 2] * rl, oacc[db][4 * jg + 3] * rl);
      *(uint2*)(smem + (((w << 5) + q) << 7) + d) = make_uint2(v0, v1);
    }
  __syncthreads();
  {
    const int qr = tid >> 1;
    const int dh = (tid & 1) << 6;
    const uint4* src = (const uint4*)(smem + (qr << 7) + dh);
    uint4* dst = (uint4*)(Ob + (long long)((b << 11) + Q0 + qr) * HID_DIM + (h << 7) + dh);
#pragma unroll
    for (int cc2 = 0; cc2 < 8; ++cc2) dst[cc2] = src[cc2];
  }
}

// ---------------- launch ----------------
extern "C" void kernel_launch(void* const* d_in, const int* in_sizes, int n_in,
                              void* d_out, int out_size, void* d_ws, size_t ws_size,
                              hipStream_t stream) {
  (void)in_sizes; (void)n_in; (void)out_size; (void)ws_size;
  const float* x = (const float*)d_in[0];
  const float* w_qkv = (const float*)d_in[1];
  const float* w_out = (const float*)d_in[2];
  float* out = (float*)d_out;
  char* ws = (char*)d_ws;

  unsigned short* xb    = (unsigned short*)(ws);              // 16 MB  [4096][2048]
  unsigned short* wqkvT = (unsigned short*)(ws + 16777216);   // 24 MB  [6144][2048]
  unsigned short* woutT = (unsigned short*)(ws + 41943040);   //  8 MB  [2048][2048]
  unsigned short* qkv   = (unsigned short*)(ws + 50331648);   // 48 MB  [4096][6144] (reused as O)
  unsigned short* Qb    = (unsigned short*)(ws + 100663296);  // 16 MB  [B,H,S,D]
  unsigned short* Kb    = (unsigned short*)(ws + 117440512);  // 16 MB  [B,H,S,D]
  unsigned short* Vt    = (unsigned short*)(ws + 134217728);  // 16 MB  [B,H,D,S]
  float* cosT = (float*)(ws + 150994944);                     // 0.5 MB [S][64]
  float* sinT = (float*)(ws + 151519232);                     // 0.5 MB
  unsigned short* Ob = qkv;

  cast_bf16<<<8192, 256, 0, stream>>>((const float4*)x, (ushort4*)xb);
  transpose_cast<<<12288, 256, 0, stream>>>(w_qkv, wqkvT, 2048, 6144);
  transpose_cast<<<4096, 256, 0, stream>>>(w_out, woutT, 2048, 2048);
  rope_tables<<<512, 256, 0, stream>>>(cosT, sinT);
  gemm_pipe<256, 256, 2, 4, unsigned short><<<384, 512, 0, stream>>>(xb, wqkvT, qkv, 4096, 6144, 2048);
  split_rope<<<2048, 256, 0, stream>>>(qkv, cosT, sinT, Qb, Kb, Vt);
  flash_attn<<<512, 256, 0, stream>>>(Qb, Kb, Vt, Ob);
  gemm_pipe<256, 128, 4, 2, float><<<256, 512, 0, stream>>>(Ob, woutT, out, 4096, 2048, 2048);
}